// Round 1
// baseline (202.664 us; speedup 1.0000x reference)
//
#include <hip/hip_runtime.h>
#include <hip/hip_bf16.h>

// GenuineAttention: x[1,2048,1024] fp32 -> (out [2048*1024], attn_weights [16*2048*2048], entropy [2048*16])
// S=2048, D_MODEL=1024, H=16, Dh=64. Strategy: bf16 MFMA everywhere, fp32 softmax math.

typedef __attribute__((ext_vector_type(8))) unsigned short u16x8;
typedef __attribute__((ext_vector_type(8))) short s16x8;
typedef __attribute__((ext_vector_type(4))) float f32x4;

__device__ __forceinline__ unsigned short f2b(float f) {
  unsigned int u = __float_as_uint(f);
  unsigned int r = (u + 0x7fffu + ((u >> 16) & 1u)) >> 16;  // RNE
  return (unsigned short)r;
}

// XOR swizzle for row-major bf16 LDS tiles (8-elem groups): kills 16-way bank conflicts
__device__ __forceinline__ int swz64(int row, int col)  { return row * 64  + (col ^ ((row & 7) << 3)); }
__device__ __forceinline__ int swz128(int row, int col) { return row * 128 + (col ^ ((row & 7) << 3)); }

// ---------------- cast fp32 -> bf16 ----------------
__global__ __launch_bounds__(256) void cast_bf16_kernel(const float* __restrict__ in,
                                                        unsigned short* __restrict__ out, int n8) {
  int i = blockIdx.x * 256 + threadIdx.x;
  if (i >= n8) return;
  const float* p = in + (size_t)i * 8;
  u16x8 o;
#pragma unroll
  for (int j = 0; j < 8; ++j) o[j] = f2b(p[j]);
  *(u16x8*)(out + (size_t)i * 8) = o;
}

// ---------------- bf16 GEMM: C[M,N] = A[M,K] * B[N,K]^T, fp32 out ----------------
// tiles 128x128, BK=64, 4 waves (each 64x64), swizzled LDS, reg-staged loads.
__global__ __launch_bounds__(256) void gemm_bf16_kernel(const unsigned short* __restrict__ A,
                                                        const unsigned short* __restrict__ B,
                                                        float* __restrict__ C,
                                                        int M, int N, int K) {
  int n0 = blockIdx.x * 128, m0 = blockIdx.y * 128;
  int tid = threadIdx.x, lane = tid & 63, w = tid >> 6;
  int wr = (w >> 1) * 64, wc = (w & 1) * 64;
  __shared__ unsigned short As[128 * 64], Bs[128 * 64];
  f32x4 acc[4][4];
#pragma unroll
  for (int i = 0; i < 4; ++i)
#pragma unroll
    for (int j = 0; j < 4; ++j) acc[i][j] = (f32x4){0.f, 0.f, 0.f, 0.f};

  for (int k0 = 0; k0 < K; k0 += 64) {
    __syncthreads();
#pragma unroll
    for (int j = 0; j < 4; ++j) {
      int flat = j * 2048 + tid * 8;      // 8192 bf16 per tile
      int row = flat >> 6, col = flat & 63;
      *(u16x8*)(As + swz64(row, col)) = *(const u16x8*)(A + (size_t)(m0 + row) * K + k0 + col);
      *(u16x8*)(Bs + swz64(row, col)) = *(const u16x8*)(B + (size_t)(n0 + row) * K + k0 + col);
    }
    __syncthreads();
#pragma unroll
    for (int kk = 0; kk < 2; ++kk) {
      s16x8 af[4], bfr[4];
#pragma unroll
      for (int i = 0; i < 4; ++i)
        af[i] = *(const s16x8*)(As + swz64(wr + i * 16 + (lane & 15), kk * 32 + ((lane >> 4) << 3)));
#pragma unroll
      for (int j = 0; j < 4; ++j)
        bfr[j] = *(const s16x8*)(Bs + swz64(wc + j * 16 + (lane & 15), kk * 32 + ((lane >> 4) << 3)));
#pragma unroll
      for (int i = 0; i < 4; ++i)
#pragma unroll
        for (int j = 0; j < 4; ++j)
          acc[i][j] = __builtin_amdgcn_mfma_f32_16x16x32_bf16(af[i], bfr[j], acc[i][j], 0, 0, 0);
    }
  }
#pragma unroll
  for (int i = 0; i < 4; ++i)
#pragma unroll
    for (int j = 0; j < 4; ++j)
#pragma unroll
      for (int r = 0; r < 4; ++r) {
        int row = m0 + wr + i * 16 + ((lane >> 4) << 2) + r;
        int col = n0 + wc + j * 16 + (lane & 15);
        C[(size_t)row * N + col] = acc[i][j][r];
      }
}

// ---------------- RoPE on q,k (fp32 in, bf16 out) ----------------
__global__ __launch_bounds__(256) void rope_kernel(const float* __restrict__ qkv,
                                                   const float* __restrict__ fcos,
                                                   const float* __restrict__ fsin,
                                                   unsigned short* __restrict__ qbf,
                                                   unsigned short* __restrict__ kbf) {
  int idx = blockIdx.x * 256 + threadIdx.x;  // [2][2048][512 pairs]
  int which = idx >> 20;
  int rem = idx & 0xFFFFF;
  int s = rem >> 9;
  int pj = rem & 511;
  int i = pj & 31;           // freq index within head
  int col = pj << 1;         // even col in [0,1024)
  const float* src = qkv + (size_t)s * 3072 + which * 1024 + col;
  float x0 = src[0], x1 = src[1];
  float c = fcos[s * 32 + i], sn = fsin[s * 32 + i];
  unsigned short* dst = which ? kbf : qbf;
  dst[(size_t)s * 1024 + col]     = f2b(x0 * c - x1 * sn);
  dst[(size_t)s * 1024 + col + 1] = f2b(x0 * sn + x1 * c);
}

// ---------------- V transpose: qkv fp32 [s][2048+h*64+d] -> vt bf16 [h][d][s] ----------------
__global__ __launch_bounds__(256) void vtrans_kernel(const float* __restrict__ qkv,
                                                     unsigned short* __restrict__ vt) {
  int sb = blockIdx.x;  // 32 blocks of 64 rows
  int h = blockIdx.y;
  __shared__ unsigned short t[64 * 65];
  int tid = threadIdx.x;
#pragma unroll
  for (int j = 0; j < 16; ++j) {
    int flat = j * 256 + tid;
    int r = flat >> 6, c = flat & 63;
    float v = qkv[(size_t)(sb * 64 + r) * 3072 + 2048 + h * 64 + c];
    t[c * 65 + r] = f2b(v);
  }
  __syncthreads();
#pragma unroll
  for (int j = 0; j < 16; ++j) {
    int flat = j * 256 + tid;
    int d = flat >> 6, si = flat & 63;
    vt[(size_t)(h * 64 + d) * 2048 + sb * 64 + si] = t[d * 65 + si];
  }
}

// ---------------- fused attention ----------------
// grid (32 qblocks of 64 rows, 16 heads), 4 waves; wave handles 16 q rows.
// pass1: online max+sumexp over all keys. pass2: recompute scores, write p (fp32 global),
// entropy acc, PV via MFMA through swizzled LDS P tile.
__global__ __launch_bounds__(256) void attn_kernel(const unsigned short* __restrict__ Qbf,
                                                   const unsigned short* __restrict__ Kbf,
                                                   const unsigned short* __restrict__ Vt,
                                                   float* __restrict__ attnw,
                                                   float* __restrict__ ent,
                                                   unsigned short* __restrict__ attno) {
  int qb = blockIdx.x, h = blockIdx.y;
  int q0 = qb * 64;
  int tid = threadIdx.x, lane = tid & 63, w = tid >> 6;
  int qr = w * 16;

  __shared__ unsigned short Qs[64 * 64];
  __shared__ unsigned short Ks[128 * 64];
  __shared__ unsigned short Vs[64 * 128];   // [d][key]
  __shared__ unsigned short Ps[64 * 128];   // [qrow][key] bf16 probs

  // stage Q once
#pragma unroll
  for (int j = 0; j < 2; ++j) {
    int flat = j * 2048 + tid * 8;
    int row = flat >> 6, col = flat & 63;
    *(u16x8*)(Qs + swz64(row, col)) = *(const u16x8*)(Qbf + (size_t)(q0 + row) * 1024 + h * 64 + col);
  }
  __syncthreads();

  s16x8 qa[2];
#pragma unroll
  for (int kk = 0; kk < 2; ++kk)
    qa[kk] = *(const s16x8*)(Qs + swz64(qr + (lane & 15), kk * 32 + ((lane >> 4) << 3)));

  float m_r[4], l_r[4];
#pragma unroll
  for (int r = 0; r < 4; ++r) { m_r[r] = -1e30f; l_r[r] = 0.f; }

  // ---- pass 1: row max + sumexp ----
  for (int kc = 0; kc < 2048; kc += 128) {
    __syncthreads();
#pragma unroll
    for (int j = 0; j < 4; ++j) {
      int flat = j * 2048 + tid * 8;
      int key = flat >> 6, col = flat & 63;
      *(u16x8*)(Ks + swz64(key, col)) = *(const u16x8*)(Kbf + (size_t)(kc + key) * 1024 + h * 64 + col);
    }
    __syncthreads();
    f32x4 sc[8];
#pragma unroll
    for (int j = 0; j < 8; ++j) {
      f32x4 c = (f32x4){0.f, 0.f, 0.f, 0.f};
#pragma unroll
      for (int kk = 0; kk < 2; ++kk) {
        s16x8 b = *(const s16x8*)(Ks + swz64(j * 16 + (lane & 15), kk * 32 + ((lane >> 4) << 3)));
        c = __builtin_amdgcn_mfma_f32_16x16x32_bf16(qa[kk], b, c, 0, 0, 0);
      }
      sc[j] = c;
    }
#pragma unroll
    for (int r = 0; r < 4; ++r) {
      float mx = -1e30f;
#pragma unroll
      for (int j = 0; j < 8; ++j) mx = fmaxf(mx, sc[j][r]);
      mx *= 0.125f;
#pragma unroll
      for (int off = 1; off < 16; off <<= 1) mx = fmaxf(mx, __shfl_xor(mx, off));
      float nm = fmaxf(m_r[r], mx);
      float sum = 0.f;
#pragma unroll
      for (int j = 0; j < 8; ++j) sum += __expf(sc[j][r] * 0.125f - nm);
#pragma unroll
      for (int off = 1; off < 16; off <<= 1) sum += __shfl_xor(sum, off);
      l_r[r] = l_r[r] * __expf(m_r[r] - nm) + sum;
      m_r[r] = nm;
    }
  }

  float linv[4], ps_r[4];
#pragma unroll
  for (int r = 0; r < 4; ++r) { linv[r] = 1.f / l_r[r]; ps_r[r] = 0.f; }
  f32x4 pv[4];
#pragma unroll
  for (int dj = 0; dj < 4; ++dj) pv[dj] = (f32x4){0.f, 0.f, 0.f, 0.f};

  // ---- pass 2: p write + entropy + PV ----
  for (int kc = 0; kc < 2048; kc += 128) {
    __syncthreads();
#pragma unroll
    for (int j = 0; j < 4; ++j) {
      int flat = j * 2048 + tid * 8;
      int key = flat >> 6, col = flat & 63;
      *(u16x8*)(Ks + swz64(key, col)) = *(const u16x8*)(Kbf + (size_t)(kc + key) * 1024 + h * 64 + col);
      int d = flat >> 7, vkey = flat & 127;
      *(u16x8*)(Vs + swz128(d, vkey)) = *(const u16x8*)(Vt + (size_t)(h * 64 + d) * 2048 + kc + vkey);
    }
    __syncthreads();
    f32x4 sc[8];
#pragma unroll
    for (int j = 0; j < 8; ++j) {
      f32x4 c = (f32x4){0.f, 0.f, 0.f, 0.f};
#pragma unroll
      for (int kk = 0; kk < 2; ++kk) {
        s16x8 b = *(const s16x8*)(Ks + swz64(j * 16 + (lane & 15), kk * 32 + ((lane >> 4) << 3)));
        c = __builtin_amdgcn_mfma_f32_16x16x32_bf16(qa[kk], b, c, 0, 0, 0);
      }
      sc[j] = c;
    }
#pragma unroll
    for (int j = 0; j < 8; ++j) {
      int colg = j * 16 + (lane & 15);
#pragma unroll
      for (int r = 0; r < 4; ++r) {
        float sv = sc[j][r] * 0.125f;
        float p = __expf(sv - m_r[r]) * linv[r];
        int lrow = qr + ((lane >> 4) << 2) + r;   // block-local q row
        attnw[((size_t)h << 22) + (size_t)(q0 + lrow) * 2048 + (size_t)(kc + colg)] = p;
        ps_r[r] += p * sv;
        Ps[swz128(lrow, colg)] = f2b(p);
      }
    }
    __syncthreads();
    s16x8 pa[4];
#pragma unroll
    for (int kk2 = 0; kk2 < 4; ++kk2)
      pa[kk2] = *(const s16x8*)(Ps + swz128(qr + (lane & 15), kk2 * 32 + ((lane >> 4) << 3)));
#pragma unroll
    for (int dj = 0; dj < 4; ++dj) {
      f32x4 c = pv[dj];
#pragma unroll
      for (int kk2 = 0; kk2 < 4; ++kk2) {
        s16x8 vb = *(const s16x8*)(Vs + swz128(dj * 16 + (lane & 15), kk2 * 32 + ((lane >> 4) << 3)));
        c = __builtin_amdgcn_mfma_f32_16x16x32_bf16(pa[kk2], vb, c, 0, 0, 0);
      }
      pv[dj] = c;
    }
  }

  // entropy: ent[q][h] = (m + ln L - sum p*s) * log2(e)
#pragma unroll
  for (int r = 0; r < 4; ++r)
#pragma unroll
    for (int off = 1; off < 16; off <<= 1) ps_r[r] += __shfl_xor(ps_r[r], off);
  if ((lane & 15) == 0) {
#pragma unroll
    for (int r = 0; r < 4; ++r) {
      int row = q0 + qr + ((lane >> 4) << 2) + r;
      ent[(size_t)row * 16 + h] = (m_r[r] + logf(l_r[r]) - ps_r[r]) * 1.44269504f;
    }
  }
  // attention output (pre-W_O), bf16
#pragma unroll
  for (int dj = 0; dj < 4; ++dj)
#pragma unroll
    for (int r = 0; r < 4; ++r) {
      int row = q0 + qr + ((lane >> 4) << 2) + r;
      int col = h * 64 + dj * 16 + (lane & 15);
      attno[(size_t)row * 1024 + col] = f2b(pv[dj][r]);
    }
}

extern "C" void kernel_launch(void* const* d_in, const int* in_sizes, int n_in,
                              void* d_out, int out_size, void* d_ws, size_t ws_size,
                              hipStream_t stream) {
  const float* x  = (const float*)d_in[0];
  const float* wq = (const float*)d_in[1];
  const float* wk = (const float*)d_in[2];
  const float* wv = (const float*)d_in[3];
  const float* wo = (const float*)d_in[4];
  const float* fc = (const float*)d_in[5];
  const float* fs = (const float*)d_in[6];

  float* out0  = (float*)d_out;
  float* attnw = out0 + (size_t)2048 * 1024;
  float* ent   = attnw + (size_t)16 * 2048 * 2048;

  char* ws = (char*)d_ws;                                   // needs ~52 MB
  unsigned short* xbf  = (unsigned short*)(ws);             // 4 MB
  unsigned short* wbf  = (unsigned short*)(ws + (4u  << 20)); // 6 MB (wq|wk|wv)
  unsigned short* wobf = (unsigned short*)(ws + (10u << 20)); // 2 MB
  float*          qkvf = (float*)        (ws + (12u << 20)); // 24 MB
  unsigned short* qbf  = (unsigned short*)(ws + (36u << 20)); // 4 MB
  unsigned short* kbf  = (unsigned short*)(ws + (40u << 20)); // 4 MB
  unsigned short* vtbf = (unsigned short*)(ws + (44u << 20)); // 4 MB
  unsigned short* aobf = (unsigned short*)(ws + (48u << 20)); // 4 MB

  cast_bf16_kernel<<<1024, 256, 0, stream>>>(x, xbf, 262144);
  cast_bf16_kernel<<<512, 256, 0, stream>>>(wq, wbf, 131072);
  cast_bf16_kernel<<<512, 256, 0, stream>>>(wk, wbf + (1u << 20), 131072);
  cast_bf16_kernel<<<512, 256, 0, stream>>>(wv, wbf + (2u << 20), 131072);
  cast_bf16_kernel<<<512, 256, 0, stream>>>(wo, wobf, 131072);

  gemm_bf16_kernel<<<dim3(24, 16), 256, 0, stream>>>(xbf, wbf, qkvf, 2048, 3072, 1024);
  rope_kernel<<<8192, 256, 0, stream>>>(qkvf, fc, fs, qbf, kbf);
  vtrans_kernel<<<dim3(32, 16), 256, 0, stream>>>(qkvf, vtbf);
  attn_kernel<<<dim3(32, 16), 256, 0, stream>>>(qbf, kbf, vtbf, attnw, ent, aobf);
  gemm_bf16_kernel<<<dim3(8, 16), 256, 0, stream>>>(aobf, wobf, out0, 2048, 1024, 1024);
}